// Round 9
// baseline (699.936 us; speedup 1.0000x reference)
//
#include <hip/hip_runtime.h>
#include <math.h>

#define BDIM 4096
#define LDIM 1024
#define DDIM 256
#define EPSF 1e-6f
#define NBLK 1024   // pair grid size (32 x 32)

typedef unsigned char uchar_t;
typedef __attribute__((ext_vector_type(4))) float floatx4;
typedef __attribute__((ext_vector_type(8))) int intx8;

__device__ inline void gl2lds16(const uchar_t* g, uchar_t* l) {
    __builtin_amdgcn_global_load_lds(
        (const __attribute__((address_space(1))) void*)g,
        (__attribute__((address_space(3))) void*)l,
        16, 0, 0);
}

// pack 4 fp32 -> 4 OCP e4m3 bytes
__device__ inline unsigned int pk4_fp8(float a, float b, float c, float d) {
    unsigned int p = __builtin_amdgcn_cvt_pk_fp8_f32(a, b, 0u, false);
    p = __builtin_amdgcn_cvt_pk_fp8_f32(c, d, p, true);
    return p;
}
__device__ inline unsigned int pk4_fp8v(float4 v) { return pk4_fp8(v.x, v.y, v.z, v.w); }

// load one 32-byte (K=128) fp8 fragment: logical chunks 2q,2q+1 of a 128B LDS row,
// stored XOR-swizzled (phys p holds logical p^(row&7); here s = row&7)
__device__ inline intx8 ldfrag(const uchar_t* row, int quad, int s) {
    const int4 lo = *(const int4*)(row + (((2 * quad) ^ s) * 16));
    const int4 hi = *(const int4*)(row + (((2 * quad + 1) ^ s) * 16));
    return (intx8){lo.x, lo.y, lo.z, lo.w, hi.x, hi.y, hi.z, hi.w};
}

#define MFMA_MX(a, b, c) \
    __builtin_amdgcn_mfma_scale_f32_16x16x128_f8f6f4( \
        (a), (b), (c), 0, 0, 0, 0x7F7F7F7F, 0, 0x7F7F7F7F)

__device__ inline void reduce_atomic(float (&rowsum)[4][4], float* __restrict__ neg,
                                     int base_i, int quad, int l16)
{
    #pragma unroll
    for (int off = 1; off < 16; off <<= 1)
        #pragma unroll
        for (int mi = 0; mi < 4; ++mi)
            #pragma unroll
            for (int r = 0; r < 4; ++r)
                rowsum[mi][r] += __shfl_xor(rowsum[mi][r], off, 64);
    if (l16 == 0) {
        #pragma unroll
        for (int mi = 0; mi < 4; ++mi)
            #pragma unroll
            for (int r = 0; r < 4; ++r)
                atomicAdd(&neg[base_i + mi * 16 + quad * 4 + r], rowsum[mi][r]);
    }
}

// ---------------- prep: fp8 convert + inverse row norms + zero neg/done ----------------
__global__ __launch_bounds__(256) void prep_kernel(
    const float* __restrict__ f, const float* __restrict__ noise,
    const float* __restrict__ ref,
    uchar_t* __restrict__ catb, uchar_t* __restrict__ refb,
    float* __restrict__ incat, float* __restrict__ inr,
    float* __restrict__ neg, unsigned int* __restrict__ done)
{
    const int b = blockIdx.x;
    const int wv = threadIdx.x >> 6, lane = threadIdx.x & 63;
    if (b < 2048) {
        const int row = b * 4 + wv;  // cat row 0..8191
        const float* src = (row < BDIM) ? noise + (size_t)row * LDIM
                                        : f + (size_t)(row - BDIM) * LDIM;
        uchar_t* dst = catb + (size_t)row * LDIM;
        float s = 0.f;
        #pragma unroll
        for (int t = 0; t < 4; ++t) {
            float4 v = *(const float4*)(src + t * 256 + lane * 4);
            s += v.x * v.x + v.y * v.y + v.z * v.z + v.w * v.w;
            *(unsigned int*)(dst + t * 256 + lane * 4) = pk4_fp8v(v);
        }
        #pragma unroll
        for (int off = 32; off > 0; off >>= 1) s += __shfl_down(s, off, 64);
        if (lane == 0) incat[row] = 1.0f / sqrtf(s);
    } else {
        const int row = (b - 2048) * 4 + wv;  // ref row 0..4095
        float4 v = *(const float4*)(ref + (size_t)row * DDIM + lane * 4);
        float s = v.x * v.x + v.y * v.y + v.z * v.z + v.w * v.w;
        *(unsigned int*)(refb + (size_t)row * DDIM + lane * 4) = pk4_fp8v(v);
        #pragma unroll
        for (int off = 32; off > 0; off >>= 1) s += __shfl_down(s, off, 64);
        if (lane == 0) inr[row] = 1.0f / sqrtf(s);
        if (threadIdx.x == 0) {
            *(float4*)(neg + (size_t)(b - 2048) * 4) = (float4){0.f, 0.f, 0.f, 0.f};
            if (b == 2048) *done = 0u;
        }
    }
}

// ---------------- fused MX-fp8 MFMA pair kernel + inline finalize ----------------
// MX-scaled K=128 MFMA with unit scales (0x7F = 2^0): same fp8 data, 2x rate.
// Last-finishing block (device-scope counter) computes the final loss.
__global__ __launch_bounds__(256, 2) void pair_mfma(
    const uchar_t* __restrict__ catb,  // 8192 x 1024 fp8 [noise; f]
    const uchar_t* __restrict__ refb,  // 4096 x 256 fp8
    const float* __restrict__ incat,   // 8192 inverse norms
    const float* __restrict__ inr,     // 4096 inverse norms
    float* __restrict__ neg, float* __restrict__ pos,
    unsigned int* __restrict__ done, float* __restrict__ out)
{
    __shared__ __align__(16) uchar_t As [128 * 128];
    __shared__ __align__(16) uchar_t Bs1[128 * 128];
    __shared__ __align__(16) uchar_t Bs2[128 * 128];
    __shared__ __align__(16) uchar_t Wl [256 * 80];  // lane-private weights, b128-safe stride

    const int tid = threadIdx.x;
    const int wid = tid >> 6, ln = tid & 63;
    const int i0 = blockIdx.y * 128, jm0 = blockIdx.x * 128;
    const int wm = (wid >> 1) * 64, wn = (wid & 1) * 64;
    const int quad = ln >> 4, l16 = ln & 15;
    const int lsw = l16 & 7;                 // read-side XOR key (row&7 == l16&7)
    const int lrow = ln >> 3;
    const int scol = ((ln & 7) ^ lrow) * 16; // staging: LDS slot s holds chunk s^(row&7)

    floatx4 acc1[4][4], acc2[4][4];

    // ================= W phase: ref_i . ref_jm (K=256), acc1 as accumulator =================
    #pragma unroll
    for (int a = 0; a < 4; ++a)
        #pragma unroll
        for (int c = 0; c < 4; ++c) acc1[a][c] = (floatx4){0.f, 0.f, 0.f, 0.f};
    {
        const uchar_t* A2 = refb + (size_t)i0 * DDIM;
        const uchar_t* B2 = refb + (size_t)jm0 * DDIM;
        for (int k0 = 0; k0 < DDIM; k0 += 128) {
            __syncthreads();
            #pragma unroll
            for (int t = 0; t < 4; ++t) {
                const int row0 = wid * 32 + t * 8;
                gl2lds16(A2 + (size_t)(row0 + lrow) * DDIM + k0 + scol, As  + row0 * 128);
                gl2lds16(B2 + (size_t)(row0 + lrow) * DDIM + k0 + scol, Bs1 + row0 * 128);
            }
            __syncthreads();
            intx8 af[4];
            #pragma unroll
            for (int mi = 0; mi < 4; ++mi)
                af[mi] = ldfrag(As + (wm + mi * 16 + l16) * 128, quad, lsw);
            #pragma unroll
            for (int ni = 0; ni < 4; ++ni) {
                intx8 bf = ldfrag(Bs1 + (wn + ni * 16 + l16) * 128, quad, lsw);
                #pragma unroll
                for (int mi = 0; mi < 4; ++mi)
                    acc1[mi][ni] = MFMA_MX(af[mi], bf, acc1[mi][ni]);
            }
        }
        // weights -> fp8 in lane-private LDS (same lane reads back: no barrier needed)
        uchar_t* wl = Wl + tid * 80;
        float icol[4];
        #pragma unroll
        for (int ni = 0; ni < 4; ++ni)
            icol[ni] = inr[jm0 + wn + ni * 16 + l16];
        #pragma unroll
        for (int mi = 0; mi < 4; ++mi) {
            float ir0 = inr[i0 + wm + mi * 16 + quad * 4 + 0];
            float ir1 = inr[i0 + wm + mi * 16 + quad * 4 + 1];
            float ir2 = inr[i0 + wm + mi * 16 + quad * 4 + 2];
            float ir3 = inr[i0 + wm + mi * 16 + quad * 4 + 3];
            unsigned int wq[4];
            #pragma unroll
            for (int ni = 0; ni < 4; ++ni)
                wq[ni] = pk4_fp8((1.0f - acc1[mi][ni][0] * ir0 * icol[ni]) * 0.5f,
                                 (1.0f - acc1[mi][ni][1] * ir1 * icol[ni]) * 0.5f,
                                 (1.0f - acc1[mi][ni][2] * ir2 * icol[ni]) * 0.5f,
                                 (1.0f - acc1[mi][ni][3] * ir3 * icol[ni]) * 0.5f);
            *(uint4*)(wl + mi * 16) = (uint4){wq[0], wq[1], wq[2], wq[3]};
        }
    }

    // ================= main: f_i . [noise_jm | f_jm] (K=1024), dual accumulate =================
    #pragma unroll
    for (int a = 0; a < 4; ++a)
        #pragma unroll
        for (int c = 0; c < 4; ++c) {
            acc1[a][c] = (floatx4){0.f, 0.f, 0.f, 0.f};
            acc2[a][c] = (floatx4){0.f, 0.f, 0.f, 0.f};
        }
    {
        const uchar_t* Ag  = catb + (size_t)(BDIM + i0) * LDIM;
        const uchar_t* B1g = catb + (size_t)jm0 * LDIM;
        const uchar_t* B2g = catb + (size_t)(BDIM + jm0) * LDIM;
        for (int k0 = 0; k0 < LDIM; k0 += 128) {
            __syncthreads();
            #pragma unroll
            for (int t = 0; t < 4; ++t) {
                const int row0 = wid * 32 + t * 8;
                const size_t go = (size_t)(row0 + lrow) * LDIM + k0 + scol;
                gl2lds16(Ag  + go, As  + row0 * 128);
                gl2lds16(B1g + go, Bs1 + row0 * 128);
                gl2lds16(B2g + go, Bs2 + row0 * 128);
            }
            __syncthreads();
            intx8 af[4];
            #pragma unroll
            for (int mi = 0; mi < 4; ++mi)
                af[mi] = ldfrag(As + (wm + mi * 16 + l16) * 128, quad, lsw);
            #pragma unroll
            for (int ni = 0; ni < 4; ++ni) {
                intx8 bf1 = ldfrag(Bs1 + (wn + ni * 16 + l16) * 128, quad, lsw);
                intx8 bf2 = ldfrag(Bs2 + (wn + ni * 16 + l16) * 128, quad, lsw);
                #pragma unroll
                for (int mi = 0; mi < 4; ++mi) {
                    acc1[mi][ni] = MFMA_MX(af[mi], bf1, acc1[mi][ni]);
                    acc2[mi][ni] = MFMA_MX(af[mi], bf2, acc2[mi][ni]);
                }
            }
        }
    }

    // ================= fused epilogue =================
    {
        const uchar_t* wl = Wl + tid * 80;
        float ifi[4][4], injn[4], injf[4];
        #pragma unroll
        for (int mi = 0; mi < 4; ++mi)
            #pragma unroll
            for (int r = 0; r < 4; ++r)
                ifi[mi][r] = incat[BDIM + i0 + wm + mi * 16 + quad * 4 + r];
        #pragma unroll
        for (int ni = 0; ni < 4; ++ni) {
            injn[ni] = incat[jm0 + wn + ni * 16 + l16];
            injf[ni] = incat[BDIM + jm0 + wn + ni * 16 + l16];
        }
        float rowsum[4][4];
        #pragma unroll
        for (int mi = 0; mi < 4; ++mi)
            #pragma unroll
            for (int r = 0; r < 4; ++r) rowsum[mi][r] = 0.f;
        #pragma unroll
        for (int mi = 0; mi < 4; ++mi) {
            unsigned int wq[4];
            *(uint4*)&wq[0] = *(const uint4*)(wl + mi * 16);
            #pragma unroll
            for (int ni = 0; ni < 4; ++ni) {
                float wv[4];
                wv[0] = __builtin_amdgcn_cvt_f32_fp8(wq[ni], 0);
                wv[1] = __builtin_amdgcn_cvt_f32_fp8(wq[ni], 1);
                wv[2] = __builtin_amdgcn_cvt_f32_fp8(wq[ni], 2);
                wv[3] = __builtin_amdgcn_cvt_f32_fp8(wq[ni], 3);
                #pragma unroll
                for (int r = 0; r < 4; ++r) {
                    int gi = i0 + wm + mi * 16 + quad * 4 + r;
                    int gc = jm0 + wn + ni * 16 + l16;
                    float e1 = __expf(acc1[mi][ni][r] * ifi[mi][r] * injn[ni]);
                    float e2 = __expf(acc2[mi][ni][r] * ifi[mi][r] * injf[ni]);
                    if (gc == gi)
                        __hip_atomic_store(&pos[gi], e1, __ATOMIC_RELAXED,
                                           __HIP_MEMORY_SCOPE_AGENT);
                    else rowsum[mi][r] += wv[r] * (e1 + e2);
                }
            }
        }
        reduce_atomic(rowsum, neg, i0 + wm, quad, l16);
    }

    // ================= last-block finalize =================
    __shared__ int is_last;
    __syncthreads();   // all waves' neg atomics + pos stores issued & drained
    if (tid == 0) {
        __threadfence();
        unsigned int old = __hip_atomic_fetch_add(done, 1u, __ATOMIC_ACQ_REL,
                                                  __HIP_MEMORY_SCOPE_AGENT);
        is_last = (old == NBLK - 1);
    }
    __syncthreads();
    if (is_last) {
        float s = 0.f;
        for (int i = tid; i < BDIM; i += 256) {
            float nv = __hip_atomic_load(&neg[i], __ATOMIC_RELAXED, __HIP_MEMORY_SCOPE_AGENT);
            float pv = __hip_atomic_load(&pos[i], __ATOMIC_RELAXED, __HIP_MEMORY_SCOPE_AGENT);
            s += logf(nv + EPSF) - logf(pv);
        }
        #pragma unroll
        for (int off = 32; off > 0; off >>= 1) s += __shfl_down(s, off, 64);
        float* wsf = (float*)As;
        if (ln == 0) wsf[wid] = s;
        __syncthreads();
        if (tid == 0) out[0] = (wsf[0] + wsf[1] + wsf[2] + wsf[3]) / (float)BDIM;
    }
}

extern "C" void kernel_launch(void* const* d_in, const int* in_sizes, int n_in,
                              void* d_out, int out_size, void* d_ws, size_t ws_size,
                              hipStream_t stream) {
    const float* f     = (const float*)d_in[0];
    const float* noise = (const float*)d_in[1];
    const float* ref   = (const float*)d_in[2];
    float* out = (float*)d_out;

    char* w = (char*)d_ws;
    uchar_t* catb      = (uchar_t*)w;                            // 8 MB
    uchar_t* refb      = (uchar_t*)(w + (size_t)8388608);        // 1 MB
    float* incat       = (float*)(w + (size_t)9437184);          // 8192 floats
    float* inr         = (float*)(w + (size_t)9469952);          // 4096 floats
    float* neg         = (float*)(w + (size_t)9486336);          // 4096 floats
    float* pos         = (float*)(w + (size_t)9502720);          // 4096 floats
    unsigned int* done = (unsigned int*)(w + (size_t)9519104);   // 1 uint

    prep_kernel<<<3072, 256, 0, stream>>>(f, noise, ref, catb, refb, incat, inr, neg, done);

    dim3 grid(BDIM / 128, BDIM / 128);
    pair_mfma<<<grid, 256, 0, stream>>>(catb, refb, incat, inr, neg, pos, done, out);
}

// Round 10
// 177.844 us; speedup vs baseline: 3.9357x; 3.9357x over previous
//
#include <hip/hip_runtime.h>
#include <math.h>

#define BDIM 4096
#define LDIM 1024
#define DDIM 256
#define EPSF 1e-6f
#define NBLK 1024   // pair grid size (32 x 32)

typedef unsigned char uchar_t;
typedef __attribute__((ext_vector_type(4))) float floatx4;
typedef __attribute__((ext_vector_type(2))) long longx2;

__device__ inline void gl2lds16(const uchar_t* g, uchar_t* l) {
    __builtin_amdgcn_global_load_lds(
        (const __attribute__((address_space(1))) void*)g,
        (__attribute__((address_space(3))) void*)l,
        16, 0, 0);
}

// pack 4 fp32 -> 4 OCP e4m3 bytes
__device__ inline unsigned int pk4_fp8(float a, float b, float c, float d) {
    unsigned int p = __builtin_amdgcn_cvt_pk_fp8_f32(a, b, 0u, false);
    p = __builtin_amdgcn_cvt_pk_fp8_f32(c, d, p, true);
    return p;
}
__device__ inline unsigned int pk4_fp8v(float4 v) { return pk4_fp8(v.x, v.y, v.z, v.w); }

__device__ inline void reduce_atomic(float (&rowsum)[4][4], float* __restrict__ neg,
                                     int base_i, int quad, int l16)
{
    #pragma unroll
    for (int off = 1; off < 16; off <<= 1)
        #pragma unroll
        for (int mi = 0; mi < 4; ++mi)
            #pragma unroll
            for (int r = 0; r < 4; ++r)
                rowsum[mi][r] += __shfl_xor(rowsum[mi][r], off, 64);
    if (l16 == 0) {
        #pragma unroll
        for (int mi = 0; mi < 4; ++mi)
            #pragma unroll
            for (int r = 0; r < 4; ++r)
                atomicAdd(&neg[base_i + mi * 16 + quad * 4 + r], rowsum[mi][r]);
    }
}

// ---------------- prep: one pass — fp8 convert + inverse row norms + zero neg/done ----
// blocks 0..8191: cat row b (b<4096: noise row b; else f row b-4096), one float4/thread
// blocks 8192..9215: 4 ref rows each (wave-per-row) + zero 4 neg entries (+done)
__global__ __launch_bounds__(256) void prep_kernel(
    const float* __restrict__ f, const float* __restrict__ noise,
    const float* __restrict__ ref,
    uchar_t* __restrict__ catb, uchar_t* __restrict__ refb,
    float* __restrict__ incat, float* __restrict__ inr,
    float* __restrict__ neg, unsigned int* __restrict__ done)
{
    const int b = blockIdx.x;
    const int tid = threadIdx.x;
    const int wv = tid >> 6, lane = tid & 63;
    if (b < 2 * BDIM) {
        const float* src = (b < BDIM) ? noise + (size_t)b * LDIM
                                      : f + (size_t)(b - BDIM) * LDIM;
        float4 v = *(const float4*)(src + tid * 4);
        *(unsigned int*)(catb + (size_t)b * LDIM + tid * 4) = pk4_fp8v(v);
        float s = v.x * v.x + v.y * v.y + v.z * v.z + v.w * v.w;
        #pragma unroll
        for (int off = 32; off > 0; off >>= 1) s += __shfl_down(s, off, 64);
        __shared__ float ws[4];
        if (lane == 0) ws[wv] = s;
        __syncthreads();
        if (tid == 0) incat[b] = 1.0f / sqrtf(ws[0] + ws[1] + ws[2] + ws[3]);
    } else {
        const int row = (b - 2 * BDIM) * 4 + wv;  // ref row 0..4095
        float4 v = *(const float4*)(ref + (size_t)row * DDIM + lane * 4);
        *(unsigned int*)(refb + (size_t)row * DDIM + lane * 4) = pk4_fp8v(v);
        float s = v.x * v.x + v.y * v.y + v.z * v.z + v.w * v.w;
        #pragma unroll
        for (int off = 32; off > 0; off >>= 1) s += __shfl_down(s, off, 64);
        if (lane == 0) inr[row] = 1.0f / sqrtf(s);
        if (tid == 0) {
            *(float4*)(neg + (size_t)(b - 2 * BDIM) * 4) = (float4){0.f, 0.f, 0.f, 0.f};
            if (b == 2 * BDIM) *done = 0u;
        }
    }
}

// ---------------- fused fp8 MFMA pair kernel + inline last-block finalize ----------------
// R8 inner structure (non-scaled fp8, K-order trick, zero-conflict XOR swizzle, no spill)
// + device-scope completion counter: last block computes the final loss.
__global__ __launch_bounds__(256, 2) void pair_mfma(
    const uchar_t* __restrict__ catb,  // 8192 x 1024 fp8 [noise; f]
    const uchar_t* __restrict__ refb,  // 4096 x 256 fp8
    const float* __restrict__ incat,   // 8192 inverse norms
    const float* __restrict__ inr,     // 4096 inverse norms
    float* __restrict__ neg, float* __restrict__ pos,
    unsigned int* __restrict__ done, float* __restrict__ out)
{
    __shared__ __align__(16) uchar_t As [128 * 128];
    __shared__ __align__(16) uchar_t Bs1[128 * 128];
    __shared__ __align__(16) uchar_t Bs2[128 * 128];
    __shared__ __align__(16) uchar_t Wl [256 * 80];  // lane-private weights, b128-safe stride

    const int tid = threadIdx.x;
    const int wid = tid >> 6, ln = tid & 63;
    const int i0 = blockIdx.y * 128, jm0 = blockIdx.x * 128;
    const int wm = (wid >> 1) * 64, wn = (wid & 1) * 64;
    const int quad = ln >> 4, l16 = ln & 15;
    const int lrow = ln >> 3;
    const int scol = ((ln & 7) ^ lrow) * 16;  // staging: LDS slot s holds chunk s^(row&7)

    floatx4 acc1[4][4], acc2[4][4];

    // ================= W phase: ref_i . ref_jm (K=256), acc1 as accumulator =================
    #pragma unroll
    for (int a = 0; a < 4; ++a)
        #pragma unroll
        for (int c = 0; c < 4; ++c) acc1[a][c] = (floatx4){0.f, 0.f, 0.f, 0.f};
    {
        const uchar_t* A2 = refb + (size_t)i0 * DDIM;
        const uchar_t* B2 = refb + (size_t)jm0 * DDIM;
        for (int k0 = 0; k0 < DDIM; k0 += 128) {
            __syncthreads();
            #pragma unroll
            for (int t = 0; t < 4; ++t) {
                const int row0 = wid * 32 + t * 8;
                gl2lds16(A2 + (size_t)(row0 + lrow) * DDIM + k0 + scol, As  + row0 * 128);
                gl2lds16(B2 + (size_t)(row0 + lrow) * DDIM + k0 + scol, Bs1 + row0 * 128);
            }
            __syncthreads();
            #pragma unroll
            for (int g = 0; g < 2; ++g) {
                const int sw = ((g * 4 + quad) ^ (l16 & 7)) * 16;
                longx2 af[4], bf[4];
                #pragma unroll
                for (int mi = 0; mi < 4; ++mi)
                    af[mi] = *(const longx2*)(As + (wm + mi * 16 + l16) * 128 + sw);
                #pragma unroll
                for (int ni = 0; ni < 4; ++ni)
                    bf[ni] = *(const longx2*)(Bs1 + (wn + ni * 16 + l16) * 128 + sw);
                #pragma unroll
                for (int h = 0; h < 2; ++h)
                    #pragma unroll
                    for (int mi = 0; mi < 4; ++mi)
                        #pragma unroll
                        for (int ni = 0; ni < 4; ++ni)
                            acc1[mi][ni] = __builtin_amdgcn_mfma_f32_16x16x32_fp8_fp8(
                                af[mi][h], bf[ni][h], acc1[mi][ni], 0, 0, 0);
            }
        }
        // weights -> fp8 in lane-private LDS (same lane reads back: no barrier needed)
        uchar_t* wl = Wl + tid * 80;
        float icol[4];
        #pragma unroll
        for (int ni = 0; ni < 4; ++ni)
            icol[ni] = inr[jm0 + wn + ni * 16 + l16];
        #pragma unroll
        for (int mi = 0; mi < 4; ++mi) {
            float ir0 = inr[i0 + wm + mi * 16 + quad * 4 + 0];
            float ir1 = inr[i0 + wm + mi * 16 + quad * 4 + 1];
            float ir2 = inr[i0 + wm + mi * 16 + quad * 4 + 2];
            float ir3 = inr[i0 + wm + mi * 16 + quad * 4 + 3];
            unsigned int wq[4];
            #pragma unroll
            for (int ni = 0; ni < 4; ++ni)
                wq[ni] = pk4_fp8((1.0f - acc1[mi][ni][0] * ir0 * icol[ni]) * 0.5f,
                                 (1.0f - acc1[mi][ni][1] * ir1 * icol[ni]) * 0.5f,
                                 (1.0f - acc1[mi][ni][2] * ir2 * icol[ni]) * 0.5f,
                                 (1.0f - acc1[mi][ni][3] * ir3 * icol[ni]) * 0.5f);
            *(uint4*)(wl + mi * 16) = (uint4){wq[0], wq[1], wq[2], wq[3]};
        }
    }

    // ================= main: f_i . [noise_jm | f_jm] (K=1024), dual accumulate =================
    #pragma unroll
    for (int a = 0; a < 4; ++a)
        #pragma unroll
        for (int c = 0; c < 4; ++c) {
            acc1[a][c] = (floatx4){0.f, 0.f, 0.f, 0.f};
            acc2[a][c] = (floatx4){0.f, 0.f, 0.f, 0.f};
        }
    {
        const uchar_t* Ag  = catb + (size_t)(BDIM + i0) * LDIM;
        const uchar_t* B1g = catb + (size_t)jm0 * LDIM;
        const uchar_t* B2g = catb + (size_t)(BDIM + jm0) * LDIM;
        for (int k0 = 0; k0 < LDIM; k0 += 128) {
            __syncthreads();
            #pragma unroll
            for (int t = 0; t < 4; ++t) {
                const int row0 = wid * 32 + t * 8;
                const size_t go = (size_t)(row0 + lrow) * LDIM + k0 + scol;
                gl2lds16(Ag  + go, As  + row0 * 128);
                gl2lds16(B1g + go, Bs1 + row0 * 128);
                gl2lds16(B2g + go, Bs2 + row0 * 128);
            }
            __syncthreads();
            #pragma unroll
            for (int g = 0; g < 2; ++g) {
                const int sw = ((g * 4 + quad) ^ (l16 & 7)) * 16;
                longx2 af[4], bf1[4], bf2[4];
                #pragma unroll
                for (int mi = 0; mi < 4; ++mi)
                    af[mi] = *(const longx2*)(As + (wm + mi * 16 + l16) * 128 + sw);
                #pragma unroll
                for (int ni = 0; ni < 4; ++ni) {
                    bf1[ni] = *(const longx2*)(Bs1 + (wn + ni * 16 + l16) * 128 + sw);
                    bf2[ni] = *(const longx2*)(Bs2 + (wn + ni * 16 + l16) * 128 + sw);
                }
                #pragma unroll
                for (int h = 0; h < 2; ++h)
                    #pragma unroll
                    for (int mi = 0; mi < 4; ++mi)
                        #pragma unroll
                        for (int ni = 0; ni < 4; ++ni) {
                            acc1[mi][ni] = __builtin_amdgcn_mfma_f32_16x16x32_fp8_fp8(
                                af[mi][h], bf1[ni][h], acc1[mi][ni], 0, 0, 0);
                            acc2[mi][ni] = __builtin_amdgcn_mfma_f32_16x16x32_fp8_fp8(
                                af[mi][h], bf2[ni][h], acc2[mi][ni], 0, 0, 0);
                        }
            }
        }
    }

    // ================= fused epilogue =================
    {
        const uchar_t* wl = Wl + tid * 80;
        float ifi[4][4], injn[4], injf[4];
        #pragma unroll
        for (int mi = 0; mi < 4; ++mi)
            #pragma unroll
            for (int r = 0; r < 4; ++r)
                ifi[mi][r] = incat[BDIM + i0 + wm + mi * 16 + quad * 4 + r];
        #pragma unroll
        for (int ni = 0; ni < 4; ++ni) {
            injn[ni] = incat[jm0 + wn + ni * 16 + l16];
            injf[ni] = incat[BDIM + jm0 + wn + ni * 16 + l16];
        }
        float rowsum[4][4];
        #pragma unroll
        for (int mi = 0; mi < 4; ++mi)
            #pragma unroll
            for (int r = 0; r < 4; ++r) rowsum[mi][r] = 0.f;
        #pragma unroll
        for (int mi = 0; mi < 4; ++mi) {
            unsigned int wq[4];
            *(uint4*)&wq[0] = *(const uint4*)(wl + mi * 16);
            #pragma unroll
            for (int ni = 0; ni < 4; ++ni) {
                float wv[4];
                wv[0] = __builtin_amdgcn_cvt_f32_fp8(wq[ni], 0);
                wv[1] = __builtin_amdgcn_cvt_f32_fp8(wq[ni], 1);
                wv[2] = __builtin_amdgcn_cvt_f32_fp8(wq[ni], 2);
                wv[3] = __builtin_amdgcn_cvt_f32_fp8(wq[ni], 3);
                #pragma unroll
                for (int r = 0; r < 4; ++r) {
                    int gi = i0 + wm + mi * 16 + quad * 4 + r;
                    int gc = jm0 + wn + ni * 16 + l16;
                    float e1 = __expf(acc1[mi][ni][r] * ifi[mi][r] * injn[ni]);
                    float e2 = __expf(acc2[mi][ni][r] * ifi[mi][r] * injf[ni]);
                    if (gc == gi)
                        __hip_atomic_store(&pos[gi], e1, __ATOMIC_RELAXED,
                                           __HIP_MEMORY_SCOPE_AGENT);
                    else rowsum[mi][r] += wv[r] * (e1 + e2);
                }
            }
        }
        reduce_atomic(rowsum, neg, i0 + wm, quad, l16);
    }

    // ================= last-block finalize =================
    __shared__ int is_last;
    __syncthreads();   // all waves' neg atomics + pos stores issued
    if (tid == 0) {
        __threadfence();
        unsigned int old = __hip_atomic_fetch_add(done, 1u, __ATOMIC_ACQ_REL,
                                                  __HIP_MEMORY_SCOPE_AGENT);
        is_last = (old == NBLK - 1);
    }
    __syncthreads();
    if (is_last) {
        float s = 0.f;
        for (int i = tid; i < BDIM; i += 256) {
            float nv = __hip_atomic_load(&neg[i], __ATOMIC_RELAXED, __HIP_MEMORY_SCOPE_AGENT);
            float pv = __hip_atomic_load(&pos[i], __ATOMIC_RELAXED, __HIP_MEMORY_SCOPE_AGENT);
            s += logf(nv + EPSF) - logf(pv);
        }
        #pragma unroll
        for (int off = 32; off > 0; off >>= 1) s += __shfl_down(s, off, 64);
        float* wsf = (float*)As;
        if (ln == 0) wsf[wid] = s;
        __syncthreads();
        if (tid == 0) out[0] = (wsf[0] + wsf[1] + wsf[2] + wsf[3]) / (float)BDIM;
    }
}

extern "C" void kernel_launch(void* const* d_in, const int* in_sizes, int n_in,
                              void* d_out, int out_size, void* d_ws, size_t ws_size,
                              hipStream_t stream) {
    const float* f     = (const float*)d_in[0];
    const float* noise = (const float*)d_in[1];
    const float* ref   = (const float*)d_in[2];
    float* out = (float*)d_out;

    char* w = (char*)d_ws;
    uchar_t* catb      = (uchar_t*)w;                            // 8 MB
    uchar_t* refb      = (uchar_t*)(w + (size_t)8388608);        // 1 MB
    float* incat       = (float*)(w + (size_t)9437184);          // 8192 floats
    float* inr         = (float*)(w + (size_t)9469952);          // 4096 floats
    float* neg         = (float*)(w + (size_t)9486336);          // 4096 floats
    float* pos         = (float*)(w + (size_t)9502720);          // 4096 floats
    unsigned int* done = (unsigned int*)(w + (size_t)9519104);   // 1 uint

    prep_kernel<<<9216, 256, 0, stream>>>(f, noise, ref, catb, refb, incat, inr, neg, done);

    dim3 grid(BDIM / 128, BDIM / 128);
    pair_mfma<<<grid, 256, 0, stream>>>(catb, refb, incat, inr, neg, pos, done, out);
}

// Round 11
// 175.741 us; speedup vs baseline: 3.9828x; 1.0120x over previous
//
#include <hip/hip_runtime.h>
#include <math.h>

#define BDIM 4096
#define LDIM 1024
#define DDIM 256
#define EPSF 1e-6f
#define NBLK 1024   // pair grid size (32 x 32)

typedef unsigned char uchar_t;
typedef __attribute__((ext_vector_type(4))) float floatx4;
typedef __attribute__((ext_vector_type(2))) long longx2;

__device__ inline void gl2lds16(const uchar_t* g, uchar_t* l) {
    __builtin_amdgcn_global_load_lds(
        (const __attribute__((address_space(1))) void*)g,
        (__attribute__((address_space(3))) void*)l,
        16, 0, 0);
}

// pack 4 fp32 -> 4 OCP e4m3 bytes
__device__ inline unsigned int pk4_fp8(float a, float b, float c, float d) {
    unsigned int p = __builtin_amdgcn_cvt_pk_fp8_f32(a, b, 0u, false);
    p = __builtin_amdgcn_cvt_pk_fp8_f32(c, d, p, true);
    return p;
}
__device__ inline unsigned int pk4_fp8v(float4 v) { return pk4_fp8(v.x, v.y, v.z, v.w); }

__device__ inline void reduce_atomic(float (&rowsum)[4][4], float* __restrict__ neg,
                                     int base_i, int quad, int l16)
{
    #pragma unroll
    for (int off = 1; off < 16; off <<= 1)
        #pragma unroll
        for (int mi = 0; mi < 4; ++mi)
            #pragma unroll
            for (int r = 0; r < 4; ++r)
                rowsum[mi][r] += __shfl_xor(rowsum[mi][r], off, 64);
    if (l16 == 0) {
        #pragma unroll
        for (int mi = 0; mi < 4; ++mi)
            #pragma unroll
            for (int r = 0; r < 4; ++r)
                atomicAdd(&neg[base_i + mi * 16 + quad * 4 + r], rowsum[mi][r]);
    }
}

// ---------------- prep: fp8 convert (16B stores) + inverse row norms + zero neg/done ----
// blocks 0..2047: 4 cat rows each, wave-per-row; lane converts 16 contiguous floats
// blocks 2048..3071: 4 ref rows each, wave-per-row + zero 4 neg entries (+done)
__global__ __launch_bounds__(256) void prep_kernel(
    const float* __restrict__ f, const float* __restrict__ noise,
    const float* __restrict__ ref,
    uchar_t* __restrict__ catb, uchar_t* __restrict__ refb,
    float* __restrict__ incat, float* __restrict__ inr,
    float* __restrict__ neg, unsigned int* __restrict__ done)
{
    const int b = blockIdx.x;
    const int tid = threadIdx.x;
    const int wv = tid >> 6, lane = tid & 63;
    if (b < 2048) {
        const int row = b * 4 + wv;  // cat row 0..8191
        const float* src = ((row < BDIM) ? noise + (size_t)row * LDIM
                                         : f + (size_t)(row - BDIM) * LDIM) + lane * 16;
        float4 v0 = *(const float4*)(src + 0);
        float4 v1 = *(const float4*)(src + 4);
        float4 v2 = *(const float4*)(src + 8);
        float4 v3 = *(const float4*)(src + 12);
        uint4 o = { pk4_fp8v(v0), pk4_fp8v(v1), pk4_fp8v(v2), pk4_fp8v(v3) };
        *(uint4*)(catb + (size_t)row * LDIM + lane * 16) = o;
        float s = v0.x*v0.x + v0.y*v0.y + v0.z*v0.z + v0.w*v0.w
                + v1.x*v1.x + v1.y*v1.y + v1.z*v1.z + v1.w*v1.w
                + v2.x*v2.x + v2.y*v2.y + v2.z*v2.z + v2.w*v2.w
                + v3.x*v3.x + v3.y*v3.y + v3.z*v3.z + v3.w*v3.w;
        #pragma unroll
        for (int off = 32; off > 0; off >>= 1) s += __shfl_down(s, off, 64);
        if (lane == 0) incat[row] = 1.0f / sqrtf(s);
    } else {
        const int row = (b - 2048) * 4 + wv;  // ref row 0..4095
        float4 v = *(const float4*)(ref + (size_t)row * DDIM + lane * 4);
        *(unsigned int*)(refb + (size_t)row * DDIM + lane * 4) = pk4_fp8v(v);
        float s = v.x * v.x + v.y * v.y + v.z * v.z + v.w * v.w;
        #pragma unroll
        for (int off = 32; off > 0; off >>= 1) s += __shfl_down(s, off, 64);
        if (lane == 0) inr[row] = 1.0f / sqrtf(s);
        if (tid == 0) {
            *(float4*)(neg + (size_t)(b - 2048) * 4) = (float4){0.f, 0.f, 0.f, 0.f};
            if (b == 2048) *done = 0u;
        }
    }
}

// ---------------- fused fp8 MFMA pair kernel + cheap last-block finalize ----------------
// R8 inner structure (non-scaled fp8, K-order trick, zero-conflict XOR swizzle, no spill).
// Completion: relaxed wave-0-only counter; waves 1-3 retire immediately.
__global__ __launch_bounds__(256, 2) void pair_mfma(
    const uchar_t* __restrict__ catb,  // 8192 x 1024 fp8 [noise; f]
    const uchar_t* __restrict__ refb,  // 4096 x 256 fp8
    const float* __restrict__ incat,   // 8192 inverse norms
    const float* __restrict__ inr,     // 4096 inverse norms
    float* __restrict__ neg, float* __restrict__ pos,
    unsigned int* __restrict__ done, float* __restrict__ out)
{
    __shared__ __align__(16) uchar_t As [128 * 128];
    __shared__ __align__(16) uchar_t Bs1[128 * 128];
    __shared__ __align__(16) uchar_t Bs2[128 * 128];
    __shared__ __align__(16) uchar_t Wl [256 * 80];  // lane-private weights, b128-safe stride

    const int tid = threadIdx.x;
    const int wid = tid >> 6, ln = tid & 63;
    const int i0 = blockIdx.y * 128, jm0 = blockIdx.x * 128;
    const int wm = (wid >> 1) * 64, wn = (wid & 1) * 64;
    const int quad = ln >> 4, l16 = ln & 15;
    const int lrow = ln >> 3;
    const int scol = ((ln & 7) ^ lrow) * 16;  // staging: LDS slot s holds chunk s^(row&7)

    floatx4 acc1[4][4], acc2[4][4];

    // ================= W phase: ref_i . ref_jm (K=256), acc1 as accumulator =================
    #pragma unroll
    for (int a = 0; a < 4; ++a)
        #pragma unroll
        for (int c = 0; c < 4; ++c) acc1[a][c] = (floatx4){0.f, 0.f, 0.f, 0.f};
    {
        const uchar_t* A2 = refb + (size_t)i0 * DDIM;
        const uchar_t* B2 = refb + (size_t)jm0 * DDIM;
        for (int k0 = 0; k0 < DDIM; k0 += 128) {
            __syncthreads();
            #pragma unroll
            for (int t = 0; t < 4; ++t) {
                const int row0 = wid * 32 + t * 8;
                gl2lds16(A2 + (size_t)(row0 + lrow) * DDIM + k0 + scol, As  + row0 * 128);
                gl2lds16(B2 + (size_t)(row0 + lrow) * DDIM + k0 + scol, Bs1 + row0 * 128);
            }
            __syncthreads();
            #pragma unroll
            for (int g = 0; g < 2; ++g) {
                const int sw = ((g * 4 + quad) ^ (l16 & 7)) * 16;
                longx2 af[4], bf[4];
                #pragma unroll
                for (int mi = 0; mi < 4; ++mi)
                    af[mi] = *(const longx2*)(As + (wm + mi * 16 + l16) * 128 + sw);
                #pragma unroll
                for (int ni = 0; ni < 4; ++ni)
                    bf[ni] = *(const longx2*)(Bs1 + (wn + ni * 16 + l16) * 128 + sw);
                #pragma unroll
                for (int h = 0; h < 2; ++h)
                    #pragma unroll
                    for (int mi = 0; mi < 4; ++mi)
                        #pragma unroll
                        for (int ni = 0; ni < 4; ++ni)
                            acc1[mi][ni] = __builtin_amdgcn_mfma_f32_16x16x32_fp8_fp8(
                                af[mi][h], bf[ni][h], acc1[mi][ni], 0, 0, 0);
            }
        }
        // weights -> fp8 in lane-private LDS (same lane reads back: no barrier needed)
        uchar_t* wl = Wl + tid * 80;
        float icol[4];
        #pragma unroll
        for (int ni = 0; ni < 4; ++ni)
            icol[ni] = inr[jm0 + wn + ni * 16 + l16];
        #pragma unroll
        for (int mi = 0; mi < 4; ++mi) {
            float ir0 = inr[i0 + wm + mi * 16 + quad * 4 + 0];
            float ir1 = inr[i0 + wm + mi * 16 + quad * 4 + 1];
            float ir2 = inr[i0 + wm + mi * 16 + quad * 4 + 2];
            float ir3 = inr[i0 + wm + mi * 16 + quad * 4 + 3];
            unsigned int wq[4];
            #pragma unroll
            for (int ni = 0; ni < 4; ++ni)
                wq[ni] = pk4_fp8((1.0f - acc1[mi][ni][0] * ir0 * icol[ni]) * 0.5f,
                                 (1.0f - acc1[mi][ni][1] * ir1 * icol[ni]) * 0.5f,
                                 (1.0f - acc1[mi][ni][2] * ir2 * icol[ni]) * 0.5f,
                                 (1.0f - acc1[mi][ni][3] * ir3 * icol[ni]) * 0.5f);
            *(uint4*)(wl + mi * 16) = (uint4){wq[0], wq[1], wq[2], wq[3]};
        }
    }

    // ================= main: f_i . [noise_jm | f_jm] (K=1024), dual accumulate =================
    #pragma unroll
    for (int a = 0; a < 4; ++a)
        #pragma unroll
        for (int c = 0; c < 4; ++c) {
            acc1[a][c] = (floatx4){0.f, 0.f, 0.f, 0.f};
            acc2[a][c] = (floatx4){0.f, 0.f, 0.f, 0.f};
        }
    {
        const uchar_t* Ag  = catb + (size_t)(BDIM + i0) * LDIM;
        const uchar_t* B1g = catb + (size_t)jm0 * LDIM;
        const uchar_t* B2g = catb + (size_t)(BDIM + jm0) * LDIM;
        for (int k0 = 0; k0 < LDIM; k0 += 128) {
            __syncthreads();
            #pragma unroll
            for (int t = 0; t < 4; ++t) {
                const int row0 = wid * 32 + t * 8;
                const size_t go = (size_t)(row0 + lrow) * LDIM + k0 + scol;
                gl2lds16(Ag  + go, As  + row0 * 128);
                gl2lds16(B1g + go, Bs1 + row0 * 128);
                gl2lds16(B2g + go, Bs2 + row0 * 128);
            }
            __syncthreads();
            #pragma unroll
            for (int g = 0; g < 2; ++g) {
                const int sw = ((g * 4 + quad) ^ (l16 & 7)) * 16;
                longx2 af[4], bf1[4], bf2[4];
                #pragma unroll
                for (int mi = 0; mi < 4; ++mi)
                    af[mi] = *(const longx2*)(As + (wm + mi * 16 + l16) * 128 + sw);
                #pragma unroll
                for (int ni = 0; ni < 4; ++ni) {
                    bf1[ni] = *(const longx2*)(Bs1 + (wn + ni * 16 + l16) * 128 + sw);
                    bf2[ni] = *(const longx2*)(Bs2 + (wn + ni * 16 + l16) * 128 + sw);
                }
                #pragma unroll
                for (int h = 0; h < 2; ++h)
                    #pragma unroll
                    for (int mi = 0; mi < 4; ++mi)
                        #pragma unroll
                        for (int ni = 0; ni < 4; ++ni) {
                            acc1[mi][ni] = __builtin_amdgcn_mfma_f32_16x16x32_fp8_fp8(
                                af[mi][h], bf1[ni][h], acc1[mi][ni], 0, 0, 0);
                            acc2[mi][ni] = __builtin_amdgcn_mfma_f32_16x16x32_fp8_fp8(
                                af[mi][h], bf2[ni][h], acc2[mi][ni], 0, 0, 0);
                        }
            }
        }
    }

    // ================= fused epilogue =================
    {
        const uchar_t* wl = Wl + tid * 80;
        float ifi[4][4], injn[4], injf[4];
        #pragma unroll
        for (int mi = 0; mi < 4; ++mi)
            #pragma unroll
            for (int r = 0; r < 4; ++r)
                ifi[mi][r] = incat[BDIM + i0 + wm + mi * 16 + quad * 4 + r];
        #pragma unroll
        for (int ni = 0; ni < 4; ++ni) {
            injn[ni] = incat[jm0 + wn + ni * 16 + l16];
            injf[ni] = incat[BDIM + jm0 + wn + ni * 16 + l16];
        }
        float rowsum[4][4];
        #pragma unroll
        for (int mi = 0; mi < 4; ++mi)
            #pragma unroll
            for (int r = 0; r < 4; ++r) rowsum[mi][r] = 0.f;
        #pragma unroll
        for (int mi = 0; mi < 4; ++mi) {
            unsigned int wq[4];
            *(uint4*)&wq[0] = *(const uint4*)(wl + mi * 16);
            #pragma unroll
            for (int ni = 0; ni < 4; ++ni) {
                float wv[4];
                wv[0] = __builtin_amdgcn_cvt_f32_fp8(wq[ni], 0);
                wv[1] = __builtin_amdgcn_cvt_f32_fp8(wq[ni], 1);
                wv[2] = __builtin_amdgcn_cvt_f32_fp8(wq[ni], 2);
                wv[3] = __builtin_amdgcn_cvt_f32_fp8(wq[ni], 3);
                #pragma unroll
                for (int r = 0; r < 4; ++r) {
                    int gi = i0 + wm + mi * 16 + quad * 4 + r;
                    int gc = jm0 + wn + ni * 16 + l16;
                    float e1 = __expf(acc1[mi][ni][r] * ifi[mi][r] * injn[ni]);
                    float e2 = __expf(acc2[mi][ni][r] * ifi[mi][r] * injf[ni]);
                    if (gc == gi)
                        __hip_atomic_store(&pos[gi], e1, __ATOMIC_RELAXED,
                                           __HIP_MEMORY_SCOPE_AGENT);
                    else rowsum[mi][r] += wv[r] * (e1 + e2);
                }
            }
        }
        reduce_atomic(rowsum, neg, i0 + wm, quad, l16);
    }

    // ================= cheap last-block finalize =================
    // Barrier drains this block's atomics (vmcnt 0). Then waves 1-3 RETIRE;
    // only wave 0 pays the counter round trip (relaxed: no per-RMW cache maintenance).
    __syncthreads();
    if (wid != 0) return;
    unsigned int old = 0;
    if (ln == 0) {
        __threadfence();
        old = __hip_atomic_fetch_add(done, 1u, __ATOMIC_RELAXED,
                                     __HIP_MEMORY_SCOPE_AGENT);
    }
    old = __shfl(old, 0, 64);
    if (old == NBLK - 1) {
        __threadfence();   // acquire side
        float s = 0.f;
        for (int i = ln; i < BDIM; i += 64) {
            float nv = __hip_atomic_load(&neg[i], __ATOMIC_RELAXED, __HIP_MEMORY_SCOPE_AGENT);
            float pv = __hip_atomic_load(&pos[i], __ATOMIC_RELAXED, __HIP_MEMORY_SCOPE_AGENT);
            s += logf(nv + EPSF) - logf(pv);
        }
        #pragma unroll
        for (int off = 32; off > 0; off >>= 1) s += __shfl_down(s, off, 64);
        if (ln == 0) out[0] = s / (float)BDIM;
    }
}

extern "C" void kernel_launch(void* const* d_in, const int* in_sizes, int n_in,
                              void* d_out, int out_size, void* d_ws, size_t ws_size,
                              hipStream_t stream) {
    const float* f     = (const float*)d_in[0];
    const float* noise = (const float*)d_in[1];
    const float* ref   = (const float*)d_in[2];
    float* out = (float*)d_out;

    char* w = (char*)d_ws;
    uchar_t* catb      = (uchar_t*)w;                            // 8 MB
    uchar_t* refb      = (uchar_t*)(w + (size_t)8388608);        // 1 MB
    float* incat       = (float*)(w + (size_t)9437184);          // 8192 floats
    float* inr         = (float*)(w + (size_t)9469952);          // 4096 floats
    float* neg         = (float*)(w + (size_t)9486336);          // 4096 floats
    float* pos         = (float*)(w + (size_t)9502720);          // 4096 floats
    unsigned int* done = (unsigned int*)(w + (size_t)9519104);   // 1 uint

    prep_kernel<<<3072, 256, 0, stream>>>(f, noise, ref, catb, refb, incat, inr, neg, done);

    dim3 grid(BDIM / 128, BDIM / 128);
    pair_mfma<<<grid, 256, 0, stream>>>(catb, refb, incat, inr, neg, pos, done, out);
}

// Round 12
// 151.973 us; speedup vs baseline: 4.6056x; 1.1564x over previous
//
#include <hip/hip_runtime.h>
#include <math.h>

#define BDIM 4096
#define LDIM 1024
#define DDIM 256
#define EPSF 1e-6f

typedef unsigned char uchar_t;
typedef __attribute__((ext_vector_type(4))) float floatx4;
typedef __attribute__((ext_vector_type(2))) long longx2;

__device__ inline void gl2lds16(const uchar_t* g, uchar_t* l) {
    __builtin_amdgcn_global_load_lds(
        (const __attribute__((address_space(1))) void*)g,
        (__attribute__((address_space(3))) void*)l,
        16, 0, 0);
}

// pack 4 fp32 -> 4 OCP e4m3 bytes
__device__ inline unsigned int pk4_fp8(float a, float b, float c, float d) {
    unsigned int p = __builtin_amdgcn_cvt_pk_fp8_f32(a, b, 0u, false);
    p = __builtin_amdgcn_cvt_pk_fp8_f32(c, d, p, true);
    return p;
}
__device__ inline unsigned int pk4_fp8v(float4 v) { return pk4_fp8(v.x, v.y, v.z, v.w); }

__device__ inline void reduce_atomic(float (&rowsum)[4][4], float* __restrict__ neg,
                                     int base_i, int quad, int l16)
{
    #pragma unroll
    for (int off = 1; off < 16; off <<= 1)
        #pragma unroll
        for (int mi = 0; mi < 4; ++mi)
            #pragma unroll
            for (int r = 0; r < 4; ++r)
                rowsum[mi][r] += __shfl_xor(rowsum[mi][r], off, 64);
    if (l16 == 0) {
        #pragma unroll
        for (int mi = 0; mi < 4; ++mi)
            #pragma unroll
            for (int r = 0; r < 4; ++r)
                atomicAdd(&neg[base_i + mi * 16 + quad * 4 + r], rowsum[mi][r]);
    }
}

// ---------------- prep: fp8 convert (16B stores) + inverse row norms + zero neg ----
// blocks 0..2047: 4 cat rows each, wave-per-row; lane converts 16 contiguous floats
// blocks 2048..3071: 4 ref rows each, wave-per-row + zero 4 neg entries
__global__ __launch_bounds__(256) void prep_kernel(
    const float* __restrict__ f, const float* __restrict__ noise,
    const float* __restrict__ ref,
    uchar_t* __restrict__ catb, uchar_t* __restrict__ refb,
    float* __restrict__ incat, float* __restrict__ inr,
    float* __restrict__ neg)
{
    const int b = blockIdx.x;
    const int tid = threadIdx.x;
    const int wv = tid >> 6, lane = tid & 63;
    if (b < 2048) {
        const int row = b * 4 + wv;  // cat row 0..8191
        const float* src = ((row < BDIM) ? noise + (size_t)row * LDIM
                                         : f + (size_t)(row - BDIM) * LDIM) + lane * 16;
        float4 v0 = *(const float4*)(src + 0);
        float4 v1 = *(const float4*)(src + 4);
        float4 v2 = *(const float4*)(src + 8);
        float4 v3 = *(const float4*)(src + 12);
        uint4 o = { pk4_fp8v(v0), pk4_fp8v(v1), pk4_fp8v(v2), pk4_fp8v(v3) };
        *(uint4*)(catb + (size_t)row * LDIM + lane * 16) = o;
        float s = v0.x*v0.x + v0.y*v0.y + v0.z*v0.z + v0.w*v0.w
                + v1.x*v1.x + v1.y*v1.y + v1.z*v1.z + v1.w*v1.w
                + v2.x*v2.x + v2.y*v2.y + v2.z*v2.z + v2.w*v2.w
                + v3.x*v3.x + v3.y*v3.y + v3.z*v3.z + v3.w*v3.w;
        #pragma unroll
        for (int off = 32; off > 0; off >>= 1) s += __shfl_down(s, off, 64);
        if (lane == 0) incat[row] = 1.0f / sqrtf(s);
    } else {
        const int row = (b - 2048) * 4 + wv;  // ref row 0..4095
        float4 v = *(const float4*)(ref + (size_t)row * DDIM + lane * 4);
        *(unsigned int*)(refb + (size_t)row * DDIM + lane * 4) = pk4_fp8v(v);
        float s = v.x * v.x + v.y * v.y + v.z * v.z + v.w * v.w;
        #pragma unroll
        for (int off = 32; off > 0; off >>= 1) s += __shfl_down(s, off, 64);
        if (lane == 0) inr[row] = 1.0f / sqrtf(s);
        if (tid == 0)
            *(float4*)(neg + (size_t)(b - 2048) * 4) = (float4){0.f, 0.f, 0.f, 0.f};
    }
}

// ---------------- fused fp8 MFMA pair kernel (R8 tail: fire-and-retire) ----------------
// Non-scaled fp8, K-order trick, zero-conflict XOR swizzle, no spill, no post-epilogue
// barrier: waves issue their neg atomics and retire immediately (CP end-of-kernel fence
// provides completion before finalize_kernel). This keeps the contended-atomic drain
// off the block-retirement critical path (R10/R11 post-mortem: in-kernel completion
// counters cost ~33 us in vmcnt(0) stalls).
__global__ __launch_bounds__(256, 2) void pair_mfma(
    const uchar_t* __restrict__ catb,  // 8192 x 1024 fp8 [noise; f]
    const uchar_t* __restrict__ refb,  // 4096 x 256 fp8
    const float* __restrict__ incat,   // 8192 inverse norms
    const float* __restrict__ inr,     // 4096 inverse norms
    float* __restrict__ neg, float* __restrict__ pos)
{
    __shared__ __align__(16) uchar_t As [128 * 128];
    __shared__ __align__(16) uchar_t Bs1[128 * 128];
    __shared__ __align__(16) uchar_t Bs2[128 * 128];
    __shared__ __align__(16) uchar_t Wl [256 * 80];  // lane-private weights, b128-safe stride

    const int tid = threadIdx.x;
    const int wid = tid >> 6, ln = tid & 63;
    const int i0 = blockIdx.y * 128, jm0 = blockIdx.x * 128;
    const int wm = (wid >> 1) * 64, wn = (wid & 1) * 64;
    const int quad = ln >> 4, l16 = ln & 15;
    const int lrow = ln >> 3;
    const int scol = ((ln & 7) ^ lrow) * 16;  // staging: LDS slot s holds chunk s^(row&7)

    floatx4 acc1[4][4], acc2[4][4];

    // ================= W phase: ref_i . ref_jm (K=256), acc1 as accumulator =================
    #pragma unroll
    for (int a = 0; a < 4; ++a)
        #pragma unroll
        for (int c = 0; c < 4; ++c) acc1[a][c] = (floatx4){0.f, 0.f, 0.f, 0.f};
    {
        const uchar_t* A2 = refb + (size_t)i0 * DDIM;
        const uchar_t* B2 = refb + (size_t)jm0 * DDIM;
        for (int k0 = 0; k0 < DDIM; k0 += 128) {
            __syncthreads();
            #pragma unroll
            for (int t = 0; t < 4; ++t) {
                const int row0 = wid * 32 + t * 8;
                gl2lds16(A2 + (size_t)(row0 + lrow) * DDIM + k0 + scol, As  + row0 * 128);
                gl2lds16(B2 + (size_t)(row0 + lrow) * DDIM + k0 + scol, Bs1 + row0 * 128);
            }
            __syncthreads();
            #pragma unroll
            for (int g = 0; g < 2; ++g) {
                const int sw = ((g * 4 + quad) ^ (l16 & 7)) * 16;
                longx2 af[4], bf[4];
                #pragma unroll
                for (int mi = 0; mi < 4; ++mi)
                    af[mi] = *(const longx2*)(As + (wm + mi * 16 + l16) * 128 + sw);
                #pragma unroll
                for (int ni = 0; ni < 4; ++ni)
                    bf[ni] = *(const longx2*)(Bs1 + (wn + ni * 16 + l16) * 128 + sw);
                #pragma unroll
                for (int h = 0; h < 2; ++h)
                    #pragma unroll
                    for (int mi = 0; mi < 4; ++mi)
                        #pragma unroll
                        for (int ni = 0; ni < 4; ++ni)
                            acc1[mi][ni] = __builtin_amdgcn_mfma_f32_16x16x32_fp8_fp8(
                                af[mi][h], bf[ni][h], acc1[mi][ni], 0, 0, 0);
            }
        }
        // weights -> fp8 in lane-private LDS (same lane reads back: no barrier needed)
        uchar_t* wl = Wl + tid * 80;
        float icol[4];
        #pragma unroll
        for (int ni = 0; ni < 4; ++ni)
            icol[ni] = inr[jm0 + wn + ni * 16 + l16];
        #pragma unroll
        for (int mi = 0; mi < 4; ++mi) {
            float ir0 = inr[i0 + wm + mi * 16 + quad * 4 + 0];
            float ir1 = inr[i0 + wm + mi * 16 + quad * 4 + 1];
            float ir2 = inr[i0 + wm + mi * 16 + quad * 4 + 2];
            float ir3 = inr[i0 + wm + mi * 16 + quad * 4 + 3];
            unsigned int wq[4];
            #pragma unroll
            for (int ni = 0; ni < 4; ++ni)
                wq[ni] = pk4_fp8((1.0f - acc1[mi][ni][0] * ir0 * icol[ni]) * 0.5f,
                                 (1.0f - acc1[mi][ni][1] * ir1 * icol[ni]) * 0.5f,
                                 (1.0f - acc1[mi][ni][2] * ir2 * icol[ni]) * 0.5f,
                                 (1.0f - acc1[mi][ni][3] * ir3 * icol[ni]) * 0.5f);
            *(uint4*)(wl + mi * 16) = (uint4){wq[0], wq[1], wq[2], wq[3]};
        }
    }

    // ================= main: f_i . [noise_jm | f_jm] (K=1024), dual accumulate =================
    #pragma unroll
    for (int a = 0; a < 4; ++a)
        #pragma unroll
        for (int c = 0; c < 4; ++c) {
            acc1[a][c] = (floatx4){0.f, 0.f, 0.f, 0.f};
            acc2[a][c] = (floatx4){0.f, 0.f, 0.f, 0.f};
        }
    {
        const uchar_t* Ag  = catb + (size_t)(BDIM + i0) * LDIM;
        const uchar_t* B1g = catb + (size_t)jm0 * LDIM;
        const uchar_t* B2g = catb + (size_t)(BDIM + jm0) * LDIM;
        for (int k0 = 0; k0 < LDIM; k0 += 128) {
            __syncthreads();
            #pragma unroll
            for (int t = 0; t < 4; ++t) {
                const int row0 = wid * 32 + t * 8;
                const size_t go = (size_t)(row0 + lrow) * LDIM + k0 + scol;
                gl2lds16(Ag  + go, As  + row0 * 128);
                gl2lds16(B1g + go, Bs1 + row0 * 128);
                gl2lds16(B2g + go, Bs2 + row0 * 128);
            }
            __syncthreads();
            #pragma unroll
            for (int g = 0; g < 2; ++g) {
                const int sw = ((g * 4 + quad) ^ (l16 & 7)) * 16;
                longx2 af[4], bf1[4], bf2[4];
                #pragma unroll
                for (int mi = 0; mi < 4; ++mi)
                    af[mi] = *(const longx2*)(As + (wm + mi * 16 + l16) * 128 + sw);
                #pragma unroll
                for (int ni = 0; ni < 4; ++ni) {
                    bf1[ni] = *(const longx2*)(Bs1 + (wn + ni * 16 + l16) * 128 + sw);
                    bf2[ni] = *(const longx2*)(Bs2 + (wn + ni * 16 + l16) * 128 + sw);
                }
                #pragma unroll
                for (int h = 0; h < 2; ++h)
                    #pragma unroll
                    for (int mi = 0; mi < 4; ++mi)
                        #pragma unroll
                        for (int ni = 0; ni < 4; ++ni) {
                            acc1[mi][ni] = __builtin_amdgcn_mfma_f32_16x16x32_fp8_fp8(
                                af[mi][h], bf1[ni][h], acc1[mi][ni], 0, 0, 0);
                            acc2[mi][ni] = __builtin_amdgcn_mfma_f32_16x16x32_fp8_fp8(
                                af[mi][h], bf2[ni][h], acc2[mi][ni], 0, 0, 0);
                        }
            }
        }
    }

    // ================= fused epilogue (fire-and-retire) =================
    {
        const uchar_t* wl = Wl + tid * 80;
        float ifi[4][4], injn[4], injf[4];
        #pragma unroll
        for (int mi = 0; mi < 4; ++mi)
            #pragma unroll
            for (int r = 0; r < 4; ++r)
                ifi[mi][r] = incat[BDIM + i0 + wm + mi * 16 + quad * 4 + r];
        #pragma unroll
        for (int ni = 0; ni < 4; ++ni) {
            injn[ni] = incat[jm0 + wn + ni * 16 + l16];
            injf[ni] = incat[BDIM + jm0 + wn + ni * 16 + l16];
        }
        float rowsum[4][4];
        #pragma unroll
        for (int mi = 0; mi < 4; ++mi)
            #pragma unroll
            for (int r = 0; r < 4; ++r) rowsum[mi][r] = 0.f;
        #pragma unroll
        for (int mi = 0; mi < 4; ++mi) {
            unsigned int wq[4];
            *(uint4*)&wq[0] = *(const uint4*)(wl + mi * 16);
            #pragma unroll
            for (int ni = 0; ni < 4; ++ni) {
                float wv[4];
                wv[0] = __builtin_amdgcn_cvt_f32_fp8(wq[ni], 0);
                wv[1] = __builtin_amdgcn_cvt_f32_fp8(wq[ni], 1);
                wv[2] = __builtin_amdgcn_cvt_f32_fp8(wq[ni], 2);
                wv[3] = __builtin_amdgcn_cvt_f32_fp8(wq[ni], 3);
                #pragma unroll
                for (int r = 0; r < 4; ++r) {
                    int gi = i0 + wm + mi * 16 + quad * 4 + r;
                    int gc = jm0 + wn + ni * 16 + l16;
                    float e1 = __expf(acc1[mi][ni][r] * ifi[mi][r] * injn[ni]);
                    float e2 = __expf(acc2[mi][ni][r] * ifi[mi][r] * injf[ni]);
                    if (gc == gi) pos[gi] = e1;   // diag: pos; both self-pairs excluded
                    else rowsum[mi][r] += wv[r] * (e1 + e2);
                }
            }
        }
        reduce_atomic(rowsum, neg, i0 + wm, quad, l16);
        // no barrier, no counter: retire with atomics in flight (CP fence completes them)
    }
}

// ---------------- finalize ----------------
__global__ __launch_bounds__(256) void finalize_kernel(const float* __restrict__ neg,
                                                       const float* __restrict__ pos,
                                                       float* __restrict__ out) {
    float s = 0.f;
    for (int i = threadIdx.x; i < BDIM; i += 256)
        s += logf(neg[i] + EPSF) - logf(pos[i]);
    #pragma unroll
    for (int off = 32; off > 0; off >>= 1) s += __shfl_down(s, off, 64);
    __shared__ float ws[4];
    int lane = threadIdx.x & 63, wid = threadIdx.x >> 6;
    if (lane == 0) ws[wid] = s;
    __syncthreads();
    if (threadIdx.x == 0) out[0] = (ws[0] + ws[1] + ws[2] + ws[3]) / (float)BDIM;
}

extern "C" void kernel_launch(void* const* d_in, const int* in_sizes, int n_in,
                              void* d_out, int out_size, void* d_ws, size_t ws_size,
                              hipStream_t stream) {
    const float* f     = (const float*)d_in[0];
    const float* noise = (const float*)d_in[1];
    const float* ref   = (const float*)d_in[2];
    float* out = (float*)d_out;

    char* w = (char*)d_ws;
    uchar_t* catb = (uchar_t*)w;                                 // 8 MB
    uchar_t* refb = (uchar_t*)(w + (size_t)8388608);             // 1 MB
    float* incat  = (float*)(w + (size_t)9437184);               // 8192 floats
    float* inr    = (float*)(w + (size_t)9469952);               // 4096 floats
    float* neg    = (float*)(w + (size_t)9486336);               // 4096 floats
    float* pos    = (float*)(w + (size_t)9502720);               // 4096 floats

    prep_kernel<<<3072, 256, 0, stream>>>(f, noise, ref, catb, refb, incat, inr, neg);

    dim3 grid(BDIM / 128, BDIM / 128);
    pair_mfma<<<grid, 256, 0, stream>>>(catb, refb, incat, inr, neg, pos);

    finalize_kernel<<<1, 256, 0, stream>>>(neg, pos, out);
}